// Round 1
// baseline (11094.975 us; speedup 1.0000x reference)
//
#include <hip/hip_runtime.h>
#include <math.h>

// Problem constants
#define BT_ROWS 4096
#define HS 2048
#define HT 4096
#define NV 32000
#define IGNORE_IDX (-100)

// Tiling
#define BM 64          // rows per block
#define BN 320         // vocab cols per block (chunk)
#define BK 32          // k-step
#define NCHUNK 100     // 32000 / 320
#define NRT 64         // 4096 / 64 row tiles
#define CTW 5          // col 16-tiles per wave (320/16/4)
#define RT 4           // row 16-tiles per block

using bf16x8 = __attribute__((ext_vector_type(8))) short;
using f32x4  = __attribute__((ext_vector_type(4))) float;

__device__ inline unsigned short f2bf(float f) {
    union { float f; unsigned u; } v; v.f = f;
    unsigned r = v.u + 0x7fffu + ((v.u >> 16) & 1u);
    return (unsigned short)(r >> 16);
}

__global__ void partial_kernel(const float* __restrict__ s_in,
                               const float* __restrict__ t_in,
                               const float* __restrict__ s_w,
                               const float* __restrict__ t_w,
                               const int*   __restrict__ target,
                               float* __restrict__ ws) {
    __shared__ alignas(16) unsigned short lA[BM][BK];   // 4 KB
    __shared__ alignas(16) unsigned short lB[BN][BK];   // 20 KB
    __shared__ float red[4][BM][5];                     // 5 KB
    __shared__ float tgtLogit[BM];

    const int tid   = threadIdx.x;
    const int rBase = blockIdx.x * BM;    // row tile (fast-varying -> co-resident per chunk)
    const int cIdx  = blockIdx.y;         // vocab chunk
    const int vBase = cIdx * BN;

    const int lane = tid & 63;
    const int w    = tid >> 6;            // wave 0..3
    const int c16  = lane & 15;
    const int q    = lane >> 4;
    const int wcol = w * (CTW * 16);      // wave's col offset within BN

    if (tid < BM) tgtLogit[tid] = 0.0f;

    f32x4 accS[RT][CTW];
    f32x4 accT[RT][CTW];
    const f32x4 zero = {0.f, 0.f, 0.f, 0.f};
    #pragma unroll
    for (int a = 0; a < RT; a++)
        #pragma unroll
        for (int b = 0; b < CTW; b++) { accS[a][b] = zero; accT[a][b] = zero; }

    const int r0 = tid >> 3;          // 0..31 (staging row within pass)
    const int cc = (tid & 7) * 4;     // 0..28 (staging col, float4)

    auto run_gemm = [&](const float* __restrict__ X, const float* __restrict__ W,
                        int K, f32x4 (&acc)[RT][CTW]) {
        for (int kk = 0; kk < K; kk += BK) {
            __syncthreads();
            // stage A: 64x32 fp32 -> bf16 LDS
            #pragma unroll
            for (int p = 0; p < 2; p++) {
                int row = r0 + p * 32;
                const float4 v = *(const float4*)&X[(size_t)(rBase + row) * K + kk + cc];
                ushort4 b;
                b.x = f2bf(v.x); b.y = f2bf(v.y); b.z = f2bf(v.z); b.w = f2bf(v.w);
                *(ushort4*)&lA[row][cc] = b;
            }
            // stage B: 320x32 fp32 -> bf16 LDS
            #pragma unroll
            for (int p = 0; p < 10; p++) {
                int row = r0 + p * 32;
                const float4 v = *(const float4*)&W[(size_t)(vBase + row) * K + kk + cc];
                ushort4 b;
                b.x = f2bf(v.x); b.y = f2bf(v.y); b.z = f2bf(v.z); b.w = f2bf(v.w);
                *(ushort4*)&lB[row][cc] = b;
            }
            __syncthreads();

            bf16x8 af[RT];
            #pragma unroll
            for (int rt = 0; rt < RT; rt++)
                af[rt] = *(const bf16x8*)&lA[rt * 16 + c16][q * 8];
            #pragma unroll
            for (int ct = 0; ct < CTW; ct++) {
                bf16x8 bf = *(const bf16x8*)&lB[wcol + ct * 16 + c16][q * 8];
                #pragma unroll
                for (int rt = 0; rt < RT; rt++)
                    acc[rt][ct] = __builtin_amdgcn_mfma_f32_16x16x32_bf16(
                        af[rt], bf, acc[rt][ct], 0, 0, 0);
            }
        }
    };

    run_gemm(s_in, s_w, HS, accS);
    run_gemm(t_in, t_w, HT, accT);

    // ---- in-block reduction ----
    // D layout: col = c16, row = q*4 + r  (within each 16x16 tile)
    #pragma unroll
    for (int rt = 0; rt < RT; rt++) {
        #pragma unroll
        for (int r = 0; r < 4; r++) {
            const int rowLocal = rt * 16 + q * 4 + r;
            float sv[CTW], tv[CTW];
            #pragma unroll
            for (int ct = 0; ct < CTW; ct++) { sv[ct] = accS[rt][ct][r]; tv[ct] = accT[rt][ct][r]; }

            // target logit pick
            const int tg = target[rBase + rowLocal];
            #pragma unroll
            for (int ct = 0; ct < CTW; ct++)
                if (vBase + wcol + ct * 16 + c16 == tg) tgtLogit[rowLocal] = sv[ct];

            float mloc = sv[0], s2 = 0.f, t2 = 0.f, dot = 0.f;
            #pragma unroll
            for (int ct = 0; ct < CTW; ct++) {
                mloc = fmaxf(mloc, sv[ct]);
                s2 += sv[ct] * sv[ct];
                t2 += tv[ct] * tv[ct];
                dot += sv[ct] * tv[ct];
            }
            #pragma unroll
            for (int mask = 1; mask < 16; mask <<= 1)
                mloc = fmaxf(mloc, __shfl_xor(mloc, mask, 64));
            float es = 0.f;
            #pragma unroll
            for (int ct = 0; ct < CTW; ct++) es += expf(sv[ct] - mloc);
            #pragma unroll
            for (int mask = 1; mask < 16; mask <<= 1) {
                es  += __shfl_xor(es,  mask, 64);
                s2  += __shfl_xor(s2,  mask, 64);
                t2  += __shfl_xor(t2,  mask, 64);
                dot += __shfl_xor(dot, mask, 64);
            }
            if (c16 == 0) {
                red[w][rowLocal][0] = mloc;
                red[w][rowLocal][1] = es;
                red[w][rowLocal][2] = dot;
                red[w][rowLocal][3] = s2;
                red[w][rowLocal][4] = t2;
            }
        }
    }
    __syncthreads();

    // combine 4 waves per row, write chunk partials
    if (tid < BM) {
        float gm = -INFINITY, gl = 0.f, gd = 0.f, gs2 = 0.f, gt2 = 0.f;
        #pragma unroll
        for (int ww = 0; ww < 4; ww++) {
            float m = red[ww][tid][0], e = red[ww][tid][1];
            float nm = fmaxf(gm, m);
            gl = gl * expf(gm - nm) + e * expf(m - nm);
            gm = nm;
            gd  += red[ww][tid][2];
            gs2 += red[ww][tid][3];
            gt2 += red[ww][tid][4];
        }
        float* o = ws + ((size_t)cIdx * BT_ROWS + rBase + tid) * 6;
        o[0] = gm; o[1] = gl; o[2] = gd; o[3] = gs2; o[4] = gt2; o[5] = tgtLogit[tid];
    }
}

__global__ void finalize_kernel(const float* __restrict__ ws,
                                const int* __restrict__ target,
                                float* __restrict__ out) {
    const int row = blockIdx.x * 256 + threadIdx.x;
    float gm = -INFINITY, gl = 0.f, gd = 0.f, gs2 = 0.f, gt2 = 0.f, gtg = 0.f;
    for (int c = 0; c < NCHUNK; c++) {
        const float* p = ws + ((size_t)c * BT_ROWS + row) * 6;
        float m = p[0], e = p[1];
        float nm = fmaxf(gm, m);
        gl = gl * expf(gm - nm) + e * expf(m - nm);
        gm = nm;
        gd += p[2]; gs2 += p[3]; gt2 += p[4]; gtg += p[5];
    }
    float logZ = gm + logf(gl);
    int tg = target[row];
    float hard = (tg != IGNORE_IDX) ? (logZ - gtg) : 0.f;
    float cosv = gd * rsqrtf(fmaxf(gs2, 1e-24f)) * rsqrtf(fmaxf(gt2, 1e-24f));
    // 0.5*hard + 0.5*(0.5*(1-cos)), all / 4096
    float contrib = (0.5f * hard + 0.25f * (1.f - cosv)) * (1.f / (float)BT_ROWS);

    __shared__ float sred[256];
    sred[threadIdx.x] = contrib;
    __syncthreads();
    for (int s = 128; s > 0; s >>= 1) {
        if (threadIdx.x < s) sred[threadIdx.x] += sred[threadIdx.x + s];
        __syncthreads();
    }
    if (threadIdx.x == 0) atomicAdd(out, sred[0]);
}

extern "C" void kernel_launch(void* const* d_in, const int* in_sizes, int n_in,
                              void* d_out, int out_size, void* d_ws, size_t ws_size,
                              hipStream_t stream) {
    const float* s_in = (const float*)d_in[0];
    const float* t_in = (const float*)d_in[1];
    const float* s_w  = (const float*)d_in[2];
    const float* t_w  = (const float*)d_in[3];
    const int*   tgt  = (const int*)d_in[4];
    float* out = (float*)d_out;
    float* ws  = (float*)d_ws;   // needs 100*4096*6*4 = 9.8 MB

    hipMemsetAsync(d_out, 0, sizeof(float), stream);

    dim3 grid(NRT, NCHUNK);   // x = row tile (fastest) -> same-chunk blocks co-resident
    partial_kernel<<<grid, 256, 0, stream>>>(s_in, t_in, s_w, t_w, tgt, ws);
    finalize_kernel<<<BT_ROWS / 256, 256, 0, stream>>>(ws, tgt, out);
}